// Round 12
// baseline (173.982 us; speedup 1.0000x reference)
//
#include <hip/hip_runtime.h>
#include <hip/hip_bf16.h>
#include <stdint.h>

// Problem geometry
#define B_   64
#define C_   512
#define L_   784      // 28*28
#define TILE 128
#define KSTEPS 25     // 24 full K-steps of 32 + 1 half step (zero-filled)
#define NPAIR 10      // unordered tile pairs (i<=j) of 4 row-tiles
#define NXCD 8
#define NROWS 65536   // 2 * B_ * C_

typedef __attribute__((ext_vector_type(8))) __bf16 bf16x8;
typedef __attribute__((ext_vector_type(4))) float  f32x4;

#define LGKM0   asm volatile("s_waitcnt lgkmcnt(0)" ::: "memory")
#define SBAR    __builtin_amdgcn_s_barrier()
#define SCHED0  __builtin_amdgcn_sched_barrier(0)

// ---------------------------------------------------------------------------
// Pass 1 (v5): NORMS ONLY. Pure streaming read of both fp32 inputs; writes
// just 256KB of per-row reciprocal norms. The bf16 intermediate is gone —
// gram stages directly from the fp32 inputs. Also zeroes partials.
// 16 lanes per row, 4 rows/wave.
__global__ __launch_bounds__(256) void norms_kernel(
    const float* __restrict__ fs, const float* __restrict__ ft,
    float* __restrict__ rnT, float* __restrict__ rnS,
    float* __restrict__ partials)
{
    if (blockIdx.x == 0 && threadIdx.x < 16) partials[threadIdx.x] = 0.0f;

    int wid  = threadIdx.x >> 6;
    int lane = threadIdx.x & 63;
    int grp  = lane >> 4;                  // row within quad
    int sub  = lane & 15;                  // lane within row
    int row  = (blockIdx.x * 4 + wid) * 4 + grp;   // 0..65535
    int mat  = row >> 15;                  // 0 -> t, 1 -> s
    int r    = row & 32767;

    const float* src = (mat == 0 ? ft : fs) + (size_t)r * L_;

    float ss = 0.0f;
#pragma unroll
    for (int it = 0; it < 12; ++it) {      // chunks 0..191
        float4 v = reinterpret_cast<const float4*>(src)[it * 16 + sub];
        ss += v.x * v.x + v.y * v.y + v.z * v.z + v.w * v.w;
    }
    if (sub < 4) {                          // chunks 192..195
        float4 v = reinterpret_cast<const float4*>(src)[192 + sub];
        ss += v.x * v.x + v.y * v.y + v.z * v.z + v.w * v.w;
    }
#pragma unroll
    for (int m = 8; m >= 1; m >>= 1) ss += __shfl_xor(ss, m, 64);
    if (sub == 0)
        (mat == 0 ? rnT : rnS)[r] = 1.0f / fmaxf(sqrtf(ss), 1e-12f);
}

// ---------------------------------------------------------------------------
// pack 8 fp32 -> bf16x8 (RNE via hardware cvt; compiler emits cvt_pk) + store
__device__ __forceinline__ void st_bf16x8(void* p, float4 a, float4 b) {
    bf16x8 w;
    w[0] = (__bf16)a.x; w[1] = (__bf16)a.y; w[2] = (__bf16)a.z; w[3] = (__bf16)a.w;
    w[4] = (__bf16)b.x; w[5] = (__bf16)b.y; w[6] = (__bf16)b.z; w[7] = (__bf16)b.w;
    *reinterpret_cast<bf16x8*>(p) = w;
}

// ---------------------------------------------------------------------------
// Pass 2 (fused, 4-phase, fp32-direct reg-staging). One block per (batch,
// pair{i<=j}), full K. Per K-step: 8 fp32 global loads issued at step TOP
// (T14 issue-early), cvt+swizzled ds_write at phase 3 (write-late), 4 MFMA
// phases in between. Panels: raw data; normalization applied in the epilogue
// via per-row reciprocal norms (verified R11): sum(G*rn_i*rn_j)^2.
// C/D layout: col = lane&15 (B-row), row = 4*(lane>>4)+q (A-row).
__global__ __launch_bounds__(512, 1) void gram_kernel(
    const float* __restrict__ fs, const float* __restrict__ ft,
    const float* __restrict__ rnT, const float* __restrict__ rnS,
    float* __restrict__ partials)
{
    // T1: bijective XCD chunk swizzle (640 = 8 XCDs x 80; 8 batches/XCD)
    int blk = (blockIdx.x % NXCD) * (B_ * NPAIR / NXCD) + blockIdx.x / NXCD;
    int b   = blk / NPAIR;
    int t   = blk % NPAIR;

    int i, j;
    if      (t < 4) { i = 0; j = t;     }
    else if (t < 7) { i = 1; j = t - 3; }
    else if (t < 9) { i = 2; j = t - 5; }
    else            { i = 3; j = 3;     }

    float wsym   = (i == j) ? 1.0f : 2.0f;
    float wcross = (i == j) ? 0.5f : 1.0f;

    // fp32 panel bases (T = fm_t, S = fm_s)
    const float* pTi = ft + (size_t)(b * C_ + i * TILE) * L_;
    const float* pTj = ft + (size_t)(b * C_ + j * TILE) * L_;
    const float* pSi = fs + (size_t)(b * C_ + i * TILE) * L_;
    const float* pSj = fs + (size_t)(b * C_ + j * TILE) * L_;

    // 3 buffers x 32KB; panel byte offsets: Ti@0, Tj@8192, Si@16384, Sj@24576
    __shared__ unsigned short lds[3 * 16384];
    __shared__ float red[8];
    __shared__ float nTi[128], nTj[128], nSi[128], nSj[128];

    int tid  = threadIdx.x;
    int wid  = tid >> 6;
    int lane = tid & 63;

    // stage the 4 norm vectors (consumed only in the epilogue)
    {
        int q = tid & 127;
        const float* srcv;
        float* dstv;
        switch (tid >> 7) {
            case 0: srcv = rnT + b * C_ + i * TILE; dstv = nTi; break;
            case 1: srcv = rnT + b * C_ + j * TILE; dstv = nTj; break;
            case 2: srcv = rnS + b * C_ + i * TILE; dstv = nSi; break;
            default: srcv = rnS + b * C_ + j * TILE; dstv = nSj; break;
        }
        dstv[q] = srcv[q];
    }

    // staging geometry: thread owns panel row sr, 8-elem k-slot sl
    int sr   = tid >> 2;                     // 0..127
    int sl   = tid & 3;                      // k-slot (8 elems)
    int koff = sl * 8;                       // k elems within step
    const size_t rowOff = (size_t)sr * L_;
    // T2 XOR-swizzled LDS write byte offset within a panel (row stride 64B)
    const int wByte = sr * 64 + ((sl ^ ((sr >> 1) & 3)) << 4);

    // fragment read addresses (same involution)
    int rA = (wid >> 2) * 64 + (lane & 15);  // A-side panel row
    int rB = (wid & 3) * 32 + (lane & 15);   // B-side panel row
    int kb = (lane >> 4) * 16;               // 16B k-slot (bytes)
    int aByte = rA * 64 + (kb ^ (((rA >> 1) & 3) << 4));
    int bByte = rB * 64 + (kb ^ (((rB >> 1) & 3) << 4));

    f32x4 att[4][2] = {}, ast[4][2] = {}, ats[4][2] = {}, ass[4][2] = {};

    unsigned short* c0 = lds;
    unsigned short* c1 = lds + 16384;
    unsigned short* c2 = lds + 32768;

#define LD4(P, OFF) (*reinterpret_cast<const float4*>((P) + (OFF)))

    // prologue: stage tiles 0 and 1 (all k valid)
#pragma unroll
    for (int pt = 0; pt < 2; ++pt) {
        unsigned short* cb = pt ? c1 : c0;
        size_t go = rowOff + pt * 32 + koff;
        float4 v0 = LD4(pTi, go), v1 = LD4(pTi, go + 4);
        float4 v2 = LD4(pTj, go), v3 = LD4(pTj, go + 4);
        float4 v4 = LD4(pSi, go), v5 = LD4(pSi, go + 4);
        float4 v6 = LD4(pSj, go), v7 = LD4(pSj, go + 4);
        char* nb = (char*)cb;
        st_bf16x8(nb + wByte,         v0, v1);
        st_bf16x8(nb + 8192  + wByte, v2, v3);
        st_bf16x8(nb + 16384 + wByte, v4, v5);
        st_bf16x8(nb + 24576 + wByte, v6, v7);
    }
    LGKM0; SBAR; SCHED0;

#define MFMA8(ACC, FA, FB)                                                             \
    _Pragma("unroll")                                                                  \
    for (int m = 0; m < 4; ++m)                                                        \
        _Pragma("unroll")                                                              \
        for (int n = 0; n < 2; ++n)                                                    \
            ACC[m][n] = __builtin_amdgcn_mfma_f32_16x16x32_bf16(FA[m], FB[n], ACC[m][n], 0, 0, 0);

// One K-step, 4 phases; DOSTAGE literal 0/1, K2 = k-elem offset of tile t+2.
#define KSTEP(BUF, NBUF, K2, DOSTAGE)                                                  \
    {                                                                                  \
        const char* bufc = (const char*)(BUF);                                         \
        float4 v0, v1, v2, v3, v4, v5, v6, v7;                                         \
        bool vld = false;                                                              \
        if (DOSTAGE) {                                                                 \
            vld = (K2) + koff < L_;                                                    \
            size_t go = rowOff + (size_t)(K2) + koff;                                  \
            if (vld) {                                                                 \
                v0 = LD4(pTi, go); v1 = LD4(pTi, go + 4);                              \
                v2 = LD4(pTj, go); v3 = LD4(pTj, go + 4);                              \
                v4 = LD4(pSi, go); v5 = LD4(pSi, go + 4);                              \
                v6 = LD4(pSj, go); v7 = LD4(pSj, go + 4);                              \
            } else {                                                                   \
                float4 z = make_float4(0.f, 0.f, 0.f, 0.f);                            \
                v0 = v1 = v2 = v3 = v4 = v5 = v6 = v7 = z;                             \
            }                                                                          \
        }                                                                              \
        bf16x8 fTi[4], fSi[4], fTj[2], fSj[2];                                         \
        /* ---- phase 0: read fTi,fTj | mfma tt ---- */                                \
        _Pragma("unroll")                                                              \
        for (int m = 0; m < 4; ++m)                                                    \
            fTi[m] = *reinterpret_cast<const bf16x8*>(bufc + aByte + m * 1024);        \
        _Pragma("unroll")                                                              \
        for (int n = 0; n < 2; ++n)                                                    \
            fTj[n] = *reinterpret_cast<const bf16x8*>(bufc + 8192 + bByte + n * 1024); \
        SBAR; LGKM0; SCHED0;                                                           \
        __builtin_amdgcn_s_setprio(1);                                                 \
        MFMA8(att, fTi, fTj);                                                          \
        __builtin_amdgcn_s_setprio(0);                                                 \
        SBAR;                                                                          \
        /* ---- phase 1: read fSj | mfma st ---- */                                    \
        _Pragma("unroll")                                                              \
        for (int n = 0; n < 2; ++n)                                                    \
            fSj[n] = *reinterpret_cast<const bf16x8*>(bufc + 24576 + bByte + n * 1024);\
        SBAR; LGKM0; SCHED0;                                                           \
        __builtin_amdgcn_s_setprio(1);                                                 \
        MFMA8(ast, fTi, fSj);                                                          \
        __builtin_amdgcn_s_setprio(0);                                                 \
        SBAR;                                                                          \
        /* ---- phase 2: read fSi | mfma ts ---- */                                    \
        _Pragma("unroll")                                                              \
        for (int m = 0; m < 4; ++m)                                                    \
            fSi[m] = *reinterpret_cast<const bf16x8*>(bufc + 16384 + aByte + m * 1024);\
        SBAR; LGKM0; SCHED0;                                                           \
        __builtin_amdgcn_s_setprio(1);                                                 \
        MFMA8(ats, fSi, fTj);                                                          \
        __builtin_amdgcn_s_setprio(0);                                                 \
        SBAR;                                                                          \
        /* ---- phase 3: mfma ss | cvt + swizzled ds_write of tile t+2 ---- */         \
        __builtin_amdgcn_s_setprio(1);                                                 \
        MFMA8(ass, fSi, fSj);                                                          \
        __builtin_amdgcn_s_setprio(0);                                                 \
        if (DOSTAGE) {                                                                 \
            char* nb = (char*)(NBUF);                                                  \
            st_bf16x8(nb + wByte,         v0, v1);                                     \
            st_bf16x8(nb + 8192  + wByte, v2, v3);                                     \
            st_bf16x8(nb + 16384 + wByte, v4, v5);                                     \
            st_bf16x8(nb + 24576 + wByte, v6, v7);                                     \
        }                                                                              \
        LGKM0; SBAR; SCHED0;                                                           \
    }

    // main loop: s = 0..22; stage tile s+2 into c2, compute tile s from c0
    for (int s = 0; s < KSTEPS - 2; ++s) {
        KSTEP(c0, c2, (s + 2) * 32, 1);
        unsigned short* tmp = c0; c0 = c1; c1 = c2; c2 = tmp;
    }
    // s = 23, 24: no staging
    KSTEP(c0, c2, 0, 0);
    { unsigned short* tmp = c0; c0 = c1; c1 = tmp; }
    KSTEP(c0, c2, 0, 0);

    // ---- epilogue: normalize-and-square with per-element rn scaling ----
    int wrow0 = (wid >> 2) * 64 + 4 * (lane >> 4);
    int wcol0 = (wid & 3) * 32 + (lane & 15);
    float v = 0.0f;
#pragma unroll
    for (int m = 0; m < 4; ++m)
#pragma unroll
        for (int q = 0; q < 4; ++q) {
            int rr = wrow0 + m * 16 + q;
            float rTi = nTi[rr], rSi = nSi[rr];
#pragma unroll
            for (int n = 0; n < 2; ++n) {
                int cc = wcol0 + n * 16;
                float rTj = nTj[cc], rSj = nSj[cc];
                float x0 = att[m][n][q] * rTi * rTj;
                float x1 = ass[m][n][q] * rSi * rSj;
                float x2 = ast[m][n][q] * rTi * rSj;
                float x3 = ats[m][n][q] * rSi * rTj;
                v += wsym * (x0 * x0 + x1 * x1)
                   - 2.0f * wcross * (x2 * x2 + x3 * x3);
            }
        }
#pragma unroll
    for (int m = 32; m >= 1; m >>= 1) v += __shfl_xor(v, m, 64);
    if (lane == 0) red[wid] = v;
    __syncthreads();
    if (tid == 0) {
        float tot = 0.0f;
#pragma unroll
        for (int q = 0; q < 8; ++q) tot += red[q];
        atomicAdd(&partials[0], tot);
    }
}

// ---------------------------------------------------------------------------
__global__ void finalize_kernel(const float* __restrict__ partials, float* __restrict__ out) {
    // mean over B*C*C = 64*512*512 = 16777216
    out[0] = partials[0] * (1.0f / 16777216.0f);
}

// ---------------------------------------------------------------------------
extern "C" void kernel_launch(void* const* d_in, const int* in_sizes, int n_in,
                              void* d_out, int out_size, void* d_ws, size_t ws_size,
                              hipStream_t stream) {
    const float* fs = (const float*)d_in[0];   // fm_s
    const float* ft = (const float*)d_in[1];   // fm_t
    float* out = (float*)d_out;

    char* ws = (char*)d_ws;
    float* partials = (float*)ws;                                  // 64 B
    float* rnT = (float*)(ws + 256);                               // 128 KB
    float* rnS = (float*)(ws + 256 + 131072);                      // 128 KB
    // total ws use: ~256 KB (bf16 intermediate eliminated)

    hipLaunchKernelGGL(norms_kernel, dim3(NROWS / 16), dim3(256), 0, stream,
                       fs, ft, rnT, rnS, partials);
    hipLaunchKernelGGL(gram_kernel, dim3(B_ * NPAIR), dim3(512), 0, stream,
                       fs, ft, rnT, rnS, partials);
    hipLaunchKernelGGL(finalize_kernel, dim3(1), dim3(1), 0, stream, partials, out);
}

// Round 13
// 132.419 us; speedup vs baseline: 1.3139x; 1.3139x over previous
//
#include <hip/hip_runtime.h>
#include <hip/hip_bf16.h>
#include <stdint.h>

// Problem geometry
#define B_   64
#define C_   512
#define L_   784      // 28*28
#define LP   800      // padded row length (25 * 32), pad is zero-filled
#define TILE 128
#define KSTEPS 25
#define NPAIR 10      // unordered tile pairs (i<=j) of 4 row-tiles
#define NXCD 8
#define NROWS 65536   // 2 * B_ * C_

#define AS1 __attribute__((address_space(1)))
#define AS3 __attribute__((address_space(3)))

typedef __attribute__((ext_vector_type(8))) __bf16 bf16x8;
typedef __attribute__((ext_vector_type(4))) float  f32x4;

#define WAITV4  asm volatile("s_waitcnt vmcnt(4)"  ::: "memory")
#define WAITV0  asm volatile("s_waitcnt vmcnt(0)"  ::: "memory")
#define LGKM0   asm volatile("s_waitcnt lgkmcnt(0)" ::: "memory")
#define SBAR    __builtin_amdgcn_s_barrier()
#define SCHED0  __builtin_amdgcn_sched_barrier(0)
#define GLD16(SRC, DST) __builtin_amdgcn_global_load_lds((AS1 const void*)(SRC), (AS3 void*)(DST), 16, 0, 0)

// ---------------------------------------------------------------------------
// round-to-nearest-even float -> bf16 bits (data has no NaN/Inf)
__device__ inline unsigned short f2bf(float x) {
    union { float f; uint32_t u; } a; a.f = x;
    uint32_t u = a.u;
    return (unsigned short)((u + 0x7fffu + ((u >> 16) & 1u)) >> 16);
}

// ---------------------------------------------------------------------------
// Pass 1 (v6): streaming fp32 -> RAW bf16 (padded LP=800) + per-row recip
// norms. 16 lanes/row, 4 rows/wave. Reads stay dense (lane-consecutive
// float4); STORES ARE 16B: adjacent lanes exchange their 8B bf16 via
// __shfl_xor(1) and even lanes write a uint4 covering two chunks (m146
// pattern: bf16x8 stores ~2x faster than ushort4). Stores have no
// dependency on the row reduction (norms applied in gram epilogue).
__global__ __launch_bounds__(256) void normalize_kernel(
    const float* __restrict__ fs, const float* __restrict__ ft,
    unsigned short* __restrict__ outT, unsigned short* __restrict__ outS,
    float* __restrict__ rnT, float* __restrict__ rnS,
    float* __restrict__ partials)
{
    if (blockIdx.x == 0 && threadIdx.x < 16) partials[threadIdx.x] = 0.0f;

    int wid  = threadIdx.x >> 6;
    int lane = threadIdx.x & 63;
    int grp  = lane >> 4;                  // row within quad
    int sub  = lane & 15;                  // lane within row
    int row  = (blockIdx.x * 4 + wid) * 4 + grp;   // 0..65535
    int mat  = row >> 15;                  // 0 -> t, 1 -> s
    int r    = row & 32767;
    bool even = !(sub & 1);

    const float* src = (mat == 0 ? ft : fs) + (size_t)r * L_;
    unsigned short* dst = (mat == 0 ? outT : outS) + (size_t)r * LP;

    float ss = 0.0f;
#pragma unroll
    for (int it = 0; it < 12; ++it) {      // chunks 0..191, all lanes active
        int c = it * 16 + sub;
        float4 v = reinterpret_cast<const float4*>(src)[c];
        ss += v.x * v.x + v.y * v.y + v.z * v.z + v.w * v.w;
        ushort4 o;
        o.x = f2bf(v.x); o.y = f2bf(v.y); o.z = f2bf(v.z); o.w = f2bf(v.w);
        uint2 mine = *reinterpret_cast<uint2*>(&o);
        uint2 part;
        part.x = (unsigned)__shfl_xor((int)mine.x, 1, 64);
        part.y = (unsigned)__shfl_xor((int)mine.y, 1, 64);
        if (even) {                         // covers chunks c (mine) and c+1
            uint4 w = make_uint4(mine.x, mine.y, part.x, part.y);
            *reinterpret_cast<uint4*>(dst + (size_t)c * 4) = w;
        }
    }
    // tail: chunks 192..195 data, 196..199 zero pad
    {
        float4 v = make_float4(0.f, 0.f, 0.f, 0.f);
        if (sub < 4) {
            v = reinterpret_cast<const float4*>(src)[192 + sub];
            ss += v.x * v.x + v.y * v.y + v.z * v.z + v.w * v.w;
        }
        ushort4 o;
        o.x = f2bf(v.x); o.y = f2bf(v.y); o.z = f2bf(v.z); o.w = f2bf(v.w);
        uint2 mine = *reinterpret_cast<uint2*>(&o);
        uint2 part;
        part.x = (unsigned)__shfl_xor((int)mine.x, 1, 64);
        part.y = (unsigned)__shfl_xor((int)mine.y, 1, 64);
        if (even && sub < 8) {              // sub=0,2: data; sub=4,6: zeros
            uint4 w = (sub < 4) ? make_uint4(mine.x, mine.y, part.x, part.y)
                                : make_uint4(0u, 0u, 0u, 0u);
            *reinterpret_cast<uint4*>(dst + (size_t)(192 + sub) * 4) = w;
        }
    }
    // 16-lane group reduction
#pragma unroll
    for (int m = 8; m >= 1; m >>= 1) ss += __shfl_xor(ss, m, 64);
    if (sub == 0)
        (mat == 0 ? rnT : rnS)[r] = 1.0f / fmaxf(sqrtf(ss), 1e-12f);
}

// ---------------------------------------------------------------------------
// Pass 2 (fused, 4-phase schedule, R8/R11 structure — verified). One block
// per (batch, pair{i<=j}), full K. Panels RAW bf16; normalization applied in
// the epilogue: sum (G*rn_i*rn_j)^2, C/D layout col=lane&15, row=4*(lane>>4)+q.
__global__ __launch_bounds__(512, 1) void gram_kernel(
    const unsigned short* __restrict__ Tn,
    const unsigned short* __restrict__ Sn,
    const float* __restrict__ rnT,
    const float* __restrict__ rnS,
    float* __restrict__ partials)
{
    // T1: bijective XCD chunk swizzle (640 = 8 XCDs x 80; 8 batches/XCD)
    int blk = (blockIdx.x % NXCD) * (B_ * NPAIR / NXCD) + blockIdx.x / NXCD;
    int b   = blk / NPAIR;
    int t   = blk % NPAIR;

    int i, j;
    if      (t < 4) { i = 0; j = t;     }
    else if (t < 7) { i = 1; j = t - 3; }
    else if (t < 9) { i = 2; j = t - 5; }
    else            { i = 3; j = 3;     }

    float wsym   = (i == j) ? 1.0f : 2.0f;
    float wcross = (i == j) ? 0.5f : 1.0f;

    const unsigned short* Ti = Tn + (size_t)b * C_ * LP + (size_t)i * TILE * LP;
    const unsigned short* Tj = Tn + (size_t)b * C_ * LP + (size_t)j * TILE * LP;
    const unsigned short* Si = Sn + (size_t)b * C_ * LP + (size_t)i * TILE * LP;
    const unsigned short* Sj = Sn + (size_t)b * C_ * LP + (size_t)j * TILE * LP;

    __shared__ unsigned short lds[3 * 16384];
    __shared__ float red[8];
    __shared__ float nTi[128], nTj[128], nSi[128], nSj[128];

    int tid  = threadIdx.x;
    int wid  = tid >> 6;
    int lane = tid & 63;

    // stage the 4 norm vectors (consumed only in the epilogue)
    {
        int q = tid & 127;
        const float* srcv;
        float* dstv;
        switch (tid >> 7) {
            case 0: srcv = rnT + b * C_ + i * TILE; dstv = nTi; break;
            case 1: srcv = rnT + b * C_ + j * TILE; dstv = nTj; break;
            case 2: srcv = rnS + b * C_ + i * TILE; dstv = nSi; break;
            default: srcv = rnS + b * C_ + j * TILE; dstv = nSj; break;
        }
        dstv[q] = srcv[q];
    }

    // staging addresses (T2 swizzle by pre-swizzled global source slot)
    int sr  = tid >> 2;                      // panel row 0..127
    int ssl = (tid & 3) ^ ((sr >> 1) & 3);   // swizzled 16B slot in row
    const size_t gOff = (size_t)sr * LP + ssl * 8;   // + k0 per step
    const int dOff = wid * 512;              // shorts; lane*16B implicit

    // fragment read addresses (swizzled read side, involution matches source)
    int rA = (wid >> 2) * 64 + (lane & 15);  // A-side panel row
    int rB = (wid & 3) * 32 + (lane & 15);   // B-side panel row
    int kb = (lane >> 4) * 16;               // 16B k-slot (bytes)
    int aByte = rA * 64 + (kb ^ (((rA >> 1) & 3) << 4));
    int bByte = rB * 64 + (kb ^ (((rB >> 1) & 3) << 4));

    f32x4 att[4][2] = {}, ast[4][2] = {}, ats[4][2] = {}, ass[4][2] = {};

    unsigned short* c0 = lds;
    unsigned short* c1 = lds + 16384;
    unsigned short* c2 = lds + 32768;

    // prologue: stage tiles 0,1 (8 GLD/thread outstanding)
    {
        GLD16(Ti + gOff, c0 + dOff);  GLD16(Tj + gOff, c0 + 4096 + dOff);
        GLD16(Si + gOff, c0 + 8192 + dOff);  GLD16(Sj + gOff, c0 + 12288 + dOff);
        GLD16(Ti + gOff + 32, c1 + dOff);  GLD16(Tj + gOff + 32, c1 + 4096 + dOff);
        GLD16(Si + gOff + 32, c1 + 8192 + dOff);  GLD16(Sj + gOff + 32, c1 + 12288 + dOff);
    }
    WAITV4;                 // tile 0 landed; tile 1's 4 loads in flight
    SBAR; SCHED0;

#define MFMA8(ACC, FA, FB)                                                             \
    _Pragma("unroll")                                                                  \
    for (int m = 0; m < 4; ++m)                                                        \
        _Pragma("unroll")                                                              \
        for (int n = 0; n < 2; ++n)                                                    \
            ACC[m][n] = __builtin_amdgcn_mfma_f32_16x16x32_bf16(FA[m], FB[n], ACC[m][n], 0, 0, 0);

#define KSTEP(BUF, NBUF, K2, DOSTAGE, ENDW)                                            \
    {                                                                                  \
        const char* bufc = (const char*)(BUF);                                         \
        bf16x8 fTi[4], fSi[4], fTj[2], fSj[2];                                         \
        /* ---- phase 0: read fTi,fTj | stage Ti(t+2) | mfma tt ---- */                \
        _Pragma("unroll")                                                              \
        for (int m = 0; m < 4; ++m)                                                    \
            fTi[m] = *reinterpret_cast<const bf16x8*>(bufc + aByte + m * 1024);        \
        _Pragma("unroll")                                                              \
        for (int n = 0; n < 2; ++n)                                                    \
            fTj[n] = *reinterpret_cast<const bf16x8*>(bufc + 8192 + bByte + n * 1024); \
        if (DOSTAGE) GLD16(Ti + gOff + (K2), (NBUF) + dOff);                           \
        SBAR; LGKM0; SCHED0;                                                           \
        __builtin_amdgcn_s_setprio(1);                                                 \
        MFMA8(att, fTi, fTj);                                                          \
        __builtin_amdgcn_s_setprio(0);                                                 \
        SBAR;                                                                          \
        /* ---- phase 1: read fSj | stage Tj(t+2) | mfma st ---- */                    \
        _Pragma("unroll")                                                              \
        for (int n = 0; n < 2; ++n)                                                    \
            fSj[n] = *reinterpret_cast<const bf16x8*>(bufc + 24576 + bByte + n * 1024);\
        if (DOSTAGE) GLD16(Tj + gOff + (K2), (NBUF) + 4096 + dOff);                    \
        SBAR; LGKM0; SCHED0;                                                           \
        __builtin_amdgcn_s_setprio(1);                                                 \
        MFMA8(ast, fTi, fSj);                                                          \
        __builtin_amdgcn_s_setprio(0);                                                 \
        SBAR;                                                                          \
        /* ---- phase 2: read fSi | stage Si(t+2) | mfma ts ---- */                    \
        _Pragma("unroll")                                                              \
        for (int m = 0; m < 4; ++m)                                                    \
            fSi[m] = *reinterpret_cast<const bf16x8*>(bufc + 16384 + aByte + m * 1024);\
        if (DOSTAGE) GLD16(Si + gOff + (K2), (NBUF) + 8192 + dOff);                    \
        SBAR; LGKM0; SCHED0;                                                           \
        __builtin_amdgcn_s_setprio(1);                                                 \
        MFMA8(ats, fSi, fTj);                                                          \
        __builtin_amdgcn_s_setprio(0);                                                 \
        SBAR;                                                                          \
        /* ---- phase 3: stage Sj(t+2) | mfma ss | end-of-step wait ---- */            \
        if (DOSTAGE) GLD16(Sj + gOff + (K2), (NBUF) + 12288 + dOff);                   \
        __builtin_amdgcn_s_setprio(1);                                                 \
        MFMA8(ass, fSi, fSj);                                                          \
        __builtin_amdgcn_s_setprio(0);                                                 \
        ENDW;                                                                          \
        SBAR; SCHED0;                                                                  \
    }

    for (int s = 0; s < KSTEPS - 2; ++s) {
        KSTEP(c0, c2, (s + 2) * 32, 1, WAITV4);
        unsigned short* tmp = c0; c0 = c1; c1 = c2; c2 = tmp;
    }
    KSTEP(c0, c2, 0, 0, WAITV0);
    { unsigned short* tmp = c0; c0 = c1; c1 = tmp; }
    KSTEP(c0, c2, 0, 0, (void)0);

    // ---- epilogue: normalize-and-square with per-element rn scaling ----
    int wrow0 = (wid >> 2) * 64 + 4 * (lane >> 4);
    int wcol0 = (wid & 3) * 32 + (lane & 15);
    float v = 0.0f;
#pragma unroll
    for (int m = 0; m < 4; ++m)
#pragma unroll
        for (int q = 0; q < 4; ++q) {
            int rr = wrow0 + m * 16 + q;
            float rTi = nTi[rr], rSi = nSi[rr];
#pragma unroll
            for (int n = 0; n < 2; ++n) {
                int cc = wcol0 + n * 16;
                float rTj = nTj[cc], rSj = nSj[cc];
                float x0 = att[m][n][q] * rTi * rTj;
                float x1 = ass[m][n][q] * rSi * rSj;
                float x2 = ast[m][n][q] * rTi * rSj;
                float x3 = ats[m][n][q] * rSi * rTj;
                v += wsym * (x0 * x0 + x1 * x1)
                   - 2.0f * wcross * (x2 * x2 + x3 * x3);
            }
        }
#pragma unroll
    for (int m = 32; m >= 1; m >>= 1) v += __shfl_xor(v, m, 64);
    if (lane == 0) red[wid] = v;
    __syncthreads();
    if (tid == 0) {
        float tot = 0.0f;
#pragma unroll
        for (int q = 0; q < 8; ++q) tot += red[q];
        atomicAdd(&partials[0], tot);
    }
}

// ---------------------------------------------------------------------------
__global__ void finalize_kernel(const float* __restrict__ partials, float* __restrict__ out) {
    // mean over B*C*C = 64*512*512 = 16777216
    out[0] = partials[0] * (1.0f / 16777216.0f);
}

// ---------------------------------------------------------------------------
extern "C" void kernel_launch(void* const* d_in, const int* in_sizes, int n_in,
                              void* d_out, int out_size, void* d_ws, size_t ws_size,
                              hipStream_t stream) {
    const float* fs = (const float*)d_in[0];   // fm_s
    const float* ft = (const float*)d_in[1];   // fm_t
    float* out = (float*)d_out;

    char* ws = (char*)d_ws;
    const size_t SZ = (size_t)B_ * C_ * LP * 2;                    // 52428800 B
    float* partials = (float*)ws;                                  // 64 B
    unsigned short* Tn = (unsigned short*)(ws + 256);
    unsigned short* Sn = (unsigned short*)(ws + 256 + SZ);
    float* rnT = (float*)(ws + 256 + 2 * SZ);                      // 128 KB
    float* rnS = (float*)(ws + 256 + 2 * SZ + 131072);             // 128 KB
    // total ws use: ~105.1 MB

    hipLaunchKernelGGL(normalize_kernel, dim3(NROWS / 16), dim3(256), 0, stream,
                       fs, ft, Tn, Sn, rnT, rnS, partials);
    hipLaunchKernelGGL(gram_kernel, dim3(B_ * NPAIR), dim3(512), 0, stream,
                       Tn, Sn, rnT, rnS, partials);
    hipLaunchKernelGGL(finalize_kernel, dim3(1), dim3(1), 0, stream, partials, out);
}

// Round 15
// 130.404 us; speedup vs baseline: 1.3342x; 1.0154x over previous
//
#include <hip/hip_runtime.h>
#include <hip/hip_bf16.h>
#include <stdint.h>

// Problem geometry
#define B_   64
#define C_   512
#define L_   784      // 28*28
#define LP   832      // padded row length: 1664B = 13 x 128B -> every row
                      // 128B-line-aligned (fixes partial-line stores); gram
                      // reads only k<800 (784..831 zero-filled)
#define TILE 128
#define KSTEPS 25
#define NPAIR 10      // unordered tile pairs (i<=j) of 4 row-tiles
#define NXCD 8
#define NROWS 65536   // 2 * B_ * C_

#define AS1 __attribute__((address_space(1)))
#define AS3 __attribute__((address_space(3)))

typedef __attribute__((ext_vector_type(8))) __bf16 bf16x8;
typedef __attribute__((ext_vector_type(4))) float  f32x4;

#define WAITV4  asm volatile("s_waitcnt vmcnt(4)"  ::: "memory")
#define WAITV0  asm volatile("s_waitcnt vmcnt(0)"  ::: "memory")
#define LGKM0   asm volatile("s_waitcnt lgkmcnt(0)" ::: "memory")
#define SBAR    __builtin_amdgcn_s_barrier()
#define SCHED0  __builtin_amdgcn_sched_barrier(0)
#define GLD16(SRC, DST) __builtin_amdgcn_global_load_lds((AS1 const void*)(SRC), (AS3 void*)(DST), 16, 0, 0)

// ---------------------------------------------------------------------------
// round-to-nearest-even float -> bf16 bits (data has no NaN/Inf)
__device__ inline unsigned short f2bf(float x) {
    union { float f; uint32_t u; } a; a.f = x;
    uint32_t u = a.u;
    return (unsigned short)((u + 0x7fffu + ((u >> 16) & 1u)) >> 16);
}

// ---------------------------------------------------------------------------
// Pass 1 (v7): streaming fp32 -> RAW bf16 (row stride LP=832, line-aligned)
// + per-row reciprocal norms (norms applied in gram epilogue — stores have
// no dependency on the reduction). 16 lanes/row, 4 rows/wave; each 16-lane
// chunk-group writes exactly one full 128B line. fp32 reads are nontemporal
// (read-once; keep LLC for the bf16 output gram re-reads).
__global__ __launch_bounds__(256) void normalize_kernel(
    const float* __restrict__ fs, const float* __restrict__ ft,
    unsigned short* __restrict__ outT, unsigned short* __restrict__ outS,
    float* __restrict__ rnT, float* __restrict__ rnS,
    float* __restrict__ partials)
{
    if (blockIdx.x == 0 && threadIdx.x < 16) partials[threadIdx.x] = 0.0f;

    int wid  = threadIdx.x >> 6;
    int lane = threadIdx.x & 63;
    int grp  = lane >> 4;                  // row within quad
    int sub  = lane & 15;                  // lane within row
    int row  = (blockIdx.x * 4 + wid) * 4 + grp;   // 0..65535
    int mat  = row >> 15;                  // 0 -> t, 1 -> s
    int r    = row & 32767;

    const f32x4* src = reinterpret_cast<const f32x4*>(
        (mat == 0 ? ft : fs) + (size_t)r * L_);
    unsigned short* dst = (mat == 0 ? outT : outS) + (size_t)r * LP;

    float ss = 0.0f;
#pragma unroll
    for (int it = 0; it < 12; ++it) {      // chunks 0..191, all lanes active
        int c = it * 16 + sub;
        f32x4 v = __builtin_nontemporal_load(src + c);
        ss += v.x * v.x + v.y * v.y + v.z * v.z + v.w * v.w;
        ushort4 o;
        o.x = f2bf(v.x); o.y = f2bf(v.y); o.z = f2bf(v.z); o.w = f2bf(v.w);
        *reinterpret_cast<ushort4*>(dst + (size_t)c * 4) = o;
    }
    // tail line [1536,1664): chunks 192..195 data (sub<4), 196..207 zeros —
    // 16 lanes cover the full 128B line
    {
        ushort4 o = make_ushort4(0, 0, 0, 0);
        if (sub < 4) {
            f32x4 v = __builtin_nontemporal_load(src + 192 + sub);
            ss += v.x * v.x + v.y * v.y + v.z * v.z + v.w * v.w;
            o.x = f2bf(v.x); o.y = f2bf(v.y); o.z = f2bf(v.z); o.w = f2bf(v.w);
        }
        *reinterpret_cast<ushort4*>(dst + (size_t)(192 + sub) * 4) = o;
    }
    // 16-lane group reduction
#pragma unroll
    for (int m = 8; m >= 1; m >>= 1) ss += __shfl_xor(ss, m, 64);
    if (sub == 0)
        (mat == 0 ? rnT : rnS)[r] = 1.0f / fmaxf(sqrtf(ss), 1e-12f);
}

// ---------------------------------------------------------------------------
// Pass 2 (fused, 4-phase schedule, R8/R11 verified structure; only LP
// changed). One block per (batch, pair{i<=j}), full K (25 steps, k<800).
// Panels RAW bf16; normalization applied in the epilogue:
// sum (G*rn_i*rn_j)^2; C/D layout col=lane&15, row=4*(lane>>4)+q.
__global__ __launch_bounds__(512, 1) void gram_kernel(
    const unsigned short* __restrict__ Tn,
    const unsigned short* __restrict__ Sn,
    const float* __restrict__ rnT,
    const float* __restrict__ rnS,
    float* __restrict__ partials)
{
    // T1: bijective XCD chunk swizzle (640 = 8 XCDs x 80; 8 batches/XCD)
    int blk = (blockIdx.x % NXCD) * (B_ * NPAIR / NXCD) + blockIdx.x / NXCD;
    int b   = blk / NPAIR;
    int t   = blk % NPAIR;

    int i, j;
    if      (t < 4) { i = 0; j = t;     }
    else if (t < 7) { i = 1; j = t - 3; }
    else if (t < 9) { i = 2; j = t - 5; }
    else            { i = 3; j = 3;     }

    float wsym   = (i == j) ? 1.0f : 2.0f;
    float wcross = (i == j) ? 0.5f : 1.0f;

    const unsigned short* Ti = Tn + (size_t)b * C_ * LP + (size_t)i * TILE * LP;
    const unsigned short* Tj = Tn + (size_t)b * C_ * LP + (size_t)j * TILE * LP;
    const unsigned short* Si = Sn + (size_t)b * C_ * LP + (size_t)i * TILE * LP;
    const unsigned short* Sj = Sn + (size_t)b * C_ * LP + (size_t)j * TILE * LP;

    __shared__ unsigned short lds[3 * 16384];
    __shared__ float red[8];
    __shared__ float nTi[128], nTj[128], nSi[128], nSj[128];

    int tid  = threadIdx.x;
    int wid  = tid >> 6;
    int lane = tid & 63;

    // stage the 4 norm vectors (consumed only in the epilogue)
    {
        int q = tid & 127;
        const float* srcv;
        float* dstv;
        switch (tid >> 7) {
            case 0: srcv = rnT + b * C_ + i * TILE; dstv = nTi; break;
            case 1: srcv = rnT + b * C_ + j * TILE; dstv = nTj; break;
            case 2: srcv = rnS + b * C_ + i * TILE; dstv = nSi; break;
            default: srcv = rnS + b * C_ + j * TILE; dstv = nSj; break;
        }
        dstv[q] = srcv[q];
    }

    // staging addresses (T2 swizzle by pre-swizzled global source slot)
    int sr  = tid >> 2;                      // panel row 0..127
    int ssl = (tid & 3) ^ ((sr >> 1) & 3);   // swizzled 16B slot in row
    const size_t gOff = (size_t)sr * LP + ssl * 8;   // + k0 per step
    const int dOff = wid * 512;              // shorts; lane*16B implicit

    // fragment read addresses (swizzled read side, involution matches source)
    int rA = (wid >> 2) * 64 + (lane & 15);  // A-side panel row
    int rB = (wid & 3) * 32 + (lane & 15);   // B-side panel row
    int kb = (lane >> 4) * 16;               // 16B k-slot (bytes)
    int aByte = rA * 64 + (kb ^ (((rA >> 1) & 3) << 4));
    int bByte = rB * 64 + (kb ^ (((rB >> 1) & 3) << 4));

    f32x4 att[4][2] = {}, ast[4][2] = {}, ats[4][2] = {}, ass[4][2] = {};

    unsigned short* c0 = lds;
    unsigned short* c1 = lds + 16384;
    unsigned short* c2 = lds + 32768;

    // prologue: stage tiles 0,1 (8 GLD/thread outstanding)
    {
        GLD16(Ti + gOff, c0 + dOff);  GLD16(Tj + gOff, c0 + 4096 + dOff);
        GLD16(Si + gOff, c0 + 8192 + dOff);  GLD16(Sj + gOff, c0 + 12288 + dOff);
        GLD16(Ti + gOff + 32, c1 + dOff);  GLD16(Tj + gOff + 32, c1 + 4096 + dOff);
        GLD16(Si + gOff + 32, c1 + 8192 + dOff);  GLD16(Sj + gOff + 32, c1 + 12288 + dOff);
    }
    WAITV4;                 // tile 0 landed; tile 1's 4 loads in flight
    SBAR; SCHED0;

#define MFMA8(ACC, FA, FB)                                                             \
    _Pragma("unroll")                                                                  \
    for (int m = 0; m < 4; ++m)                                                        \
        _Pragma("unroll")                                                              \
        for (int n = 0; n < 2; ++n)                                                    \
            ACC[m][n] = __builtin_amdgcn_mfma_f32_16x16x32_bf16(FA[m], FB[n], ACC[m][n], 0, 0, 0);

#define KSTEP(BUF, NBUF, K2, DOSTAGE, ENDW)                                            \
    {                                                                                  \
        const char* bufc = (const char*)(BUF);                                         \
        bf16x8 fTi[4], fSi[4], fTj[2], fSj[2];                                         \
        /* ---- phase 0: read fTi,fTj | stage Ti(t+2) | mfma tt ---- */                \
        _Pragma("unroll")                                                              \
        for (int m = 0; m < 4; ++m)                                                    \
            fTi[m] = *reinterpret_cast<const bf16x8*>(bufc + aByte + m * 1024);        \
        _Pragma("unroll")                                                              \
        for (int n = 0; n < 2; ++n)                                                    \
            fTj[n] = *reinterpret_cast<const bf16x8*>(bufc + 8192 + bByte + n * 1024); \
        if (DOSTAGE) GLD16(Ti + gOff + (K2), (NBUF) + dOff);                           \
        SBAR; LGKM0; SCHED0;                                                           \
        __builtin_amdgcn_s_setprio(1);                                                 \
        MFMA8(att, fTi, fTj);                                                          \
        __builtin_amdgcn_s_setprio(0);                                                 \
        SBAR;                                                                          \
        /* ---- phase 1: read fSj | stage Tj(t+2) | mfma st ---- */                    \
        _Pragma("unroll")                                                              \
        for (int n = 0; n < 2; ++n)                                                    \
            fSj[n] = *reinterpret_cast<const bf16x8*>(bufc + 24576 + bByte + n * 1024);\
        if (DOSTAGE) GLD16(Tj + gOff + (K2), (NBUF) + 4096 + dOff);                    \
        SBAR; LGKM0; SCHED0;                                                           \
        __builtin_amdgcn_s_setprio(1);                                                 \
        MFMA8(ast, fTi, fSj);                                                          \
        __builtin_amdgcn_s_setprio(0);                                                 \
        SBAR;                                                                          \
        /* ---- phase 2: read fSi | stage Si(t+2) | mfma ts ---- */                    \
        _Pragma("unroll")                                                              \
        for (int m = 0; m < 4; ++m)                                                    \
            fSi[m] = *reinterpret_cast<const bf16x8*>(bufc + 16384 + aByte + m * 1024);\
        if (DOSTAGE) GLD16(Si + gOff + (K2), (NBUF) + 8192 + dOff);                    \
        SBAR; LGKM0; SCHED0;                                                           \
        __builtin_amdgcn_s_setprio(1);                                                 \
        MFMA8(ats, fSi, fTj);                                                          \
        __builtin_amdgcn_s_setprio(0);                                                 \
        SBAR;                                                                          \
        /* ---- phase 3: stage Sj(t+2) | mfma ss | end-of-step wait ---- */            \
        if (DOSTAGE) GLD16(Sj + gOff + (K2), (NBUF) + 12288 + dOff);                   \
        __builtin_amdgcn_s_setprio(1);                                                 \
        MFMA8(ass, fSi, fSj);                                                          \
        __builtin_amdgcn_s_setprio(0);                                                 \
        ENDW;                                                                          \
        SBAR; SCHED0;                                                                  \
    }

    for (int s = 0; s < KSTEPS - 2; ++s) {
        KSTEP(c0, c2, (s + 2) * 32, 1, WAITV4);
        unsigned short* tmp = c0; c0 = c1; c1 = c2; c2 = tmp;
    }
    KSTEP(c0, c2, 0, 0, WAITV0);
    { unsigned short* tmp = c0; c0 = c1; c1 = tmp; }
    KSTEP(c0, c2, 0, 0, (void)0);

    // ---- epilogue: normalize-and-square with per-element rn scaling ----
    int wrow0 = (wid >> 2) * 64 + 4 * (lane >> 4);
    int wcol0 = (wid & 3) * 32 + (lane & 15);
    float v = 0.0f;
#pragma unroll
    for (int m = 0; m < 4; ++m)
#pragma unroll
        for (int q = 0; q < 4; ++q) {
            int rr = wrow0 + m * 16 + q;
            float rTi = nTi[rr], rSi = nSi[rr];
#pragma unroll
            for (int n = 0; n < 2; ++n) {
                int cc = wcol0 + n * 16;
                float rTj = nTj[cc], rSj = nSj[cc];
                float x0 = att[m][n][q] * rTi * rTj;
                float x1 = ass[m][n][q] * rSi * rSj;
                float x2 = ast[m][n][q] * rTi * rSj;
                float x3 = ats[m][n][q] * rSi * rTj;
                v += wsym * (x0 * x0 + x1 * x1)
                   - 2.0f * wcross * (x2 * x2 + x3 * x3);
            }
        }
#pragma unroll
    for (int m = 32; m >= 1; m >>= 1) v += __shfl_xor(v, m, 64);
    if (lane == 0) red[wid] = v;
    __syncthreads();
    if (tid == 0) {
        float tot = 0.0f;
#pragma unroll
        for (int q = 0; q < 8; ++q) tot += red[q];
        atomicAdd(&partials[0], tot);
    }
}

// ---------------------------------------------------------------------------
__global__ void finalize_kernel(const float* __restrict__ partials, float* __restrict__ out) {
    // mean over B*C*C = 64*512*512 = 16777216
    out[0] = partials[0] * (1.0f / 16777216.0f);
}

// ---------------------------------------------------------------------------
extern "C" void kernel_launch(void* const* d_in, const int* in_sizes, int n_in,
                              void* d_out, int out_size, void* d_ws, size_t ws_size,
                              hipStream_t stream) {
    const float* fs = (const float*)d_in[0];   // fm_s
    const float* ft = (const float*)d_in[1];   // fm_t
    float* out = (float*)d_out;

    char* ws = (char*)d_ws;
    const size_t SZ = (size_t)B_ * C_ * LP * 2;                    // 54525952 B
    float* partials = (float*)ws;                                  // 64 B
    unsigned short* Tn = (unsigned short*)(ws + 256);
    unsigned short* Sn = (unsigned short*)(ws + 256 + SZ);
    float* rnT = (float*)(ws + 256 + 2 * SZ);                      // 128 KB
    float* rnS = (float*)(ws + 256 + 2 * SZ + 131072);             // 128 KB
    // total ws use: ~109.3 MB

    hipLaunchKernelGGL(normalize_kernel, dim3(NROWS / 16), dim3(256), 0, stream,
                       fs, ft, Tn, Sn, rnT, rnS, partials);
    hipLaunchKernelGGL(gram_kernel, dim3(B_ * NPAIR), dim3(512), 0, stream,
                       Tn, Sn, rnT, rnS, partials);
    hipLaunchKernelGGL(finalize_kernel, dim3(1), dim3(1), 0, stream, partials, out);
}

// Round 16
// 126.148 us; speedup vs baseline: 1.3792x; 1.0337x over previous
//
#include <hip/hip_runtime.h>
#include <hip/hip_bf16.h>
#include <stdint.h>

// Problem geometry
#define B_   64
#define C_   512
#define L_   784      // 28*28
#define LP   832      // padded row length: 1664B = 13 x 128B -> every row
                      // 128B-line-aligned (fixes partial-line stores); gram
                      // reads only k<800 (784..831 zero-filled)
#define TILE 128
#define KSTEPS 25
#define NPAIR 10      // unordered tile pairs (i<=j) of 4 row-tiles
#define NXCD 8
#define NROWS 65536   // 2 * B_ * C_

#define AS1 __attribute__((address_space(1)))
#define AS3 __attribute__((address_space(3)))

typedef __attribute__((ext_vector_type(8))) __bf16 bf16x8;
typedef __attribute__((ext_vector_type(4))) float  f32x4;

#define WAITV4  asm volatile("s_waitcnt vmcnt(4)"  ::: "memory")
#define WAITV0  asm volatile("s_waitcnt vmcnt(0)"  ::: "memory")
#define LGKM0   asm volatile("s_waitcnt lgkmcnt(0)" ::: "memory")
#define SBAR    __builtin_amdgcn_s_barrier()
#define SCHED0  __builtin_amdgcn_sched_barrier(0)
#define GLD16(SRC, DST) __builtin_amdgcn_global_load_lds((AS1 const void*)(SRC), (AS3 void*)(DST), 16, 0, 0)

// ---------------------------------------------------------------------------
// round-to-nearest-even float -> bf16 bits (data has no NaN/Inf)
__device__ inline unsigned short f2bf(float x) {
    union { float f; uint32_t u; } a; a.f = x;
    uint32_t u = a.u;
    return (unsigned short)((u + 0x7fffu + ((u >> 16) & 1u)) >> 16);
}

// ---------------------------------------------------------------------------
// Pass 1 (v8): streaming fp32 -> RAW bf16 (row stride LP=832, line-aligned)
// + per-row reciprocal norms (norms applied in gram epilogue — stores have
// no dependency on the reduction). 16 lanes/row, 4 rows/wave; each 16-lane
// chunk-group writes exactly one full 128B line. PLAIN loads (no nt): the
// read-only fp32 input partially persists in LLC across timed replays
// (R10 warm FETCH = half the input) — nt hints killed that reuse (R15).
__global__ __launch_bounds__(256) void normalize_kernel(
    const float* __restrict__ fs, const float* __restrict__ ft,
    unsigned short* __restrict__ outT, unsigned short* __restrict__ outS,
    float* __restrict__ rnT, float* __restrict__ rnS,
    float* __restrict__ partials)
{
    if (blockIdx.x == 0 && threadIdx.x < 16) partials[threadIdx.x] = 0.0f;

    int wid  = threadIdx.x >> 6;
    int lane = threadIdx.x & 63;
    int grp  = lane >> 4;                  // row within quad
    int sub  = lane & 15;                  // lane within row
    int row  = (blockIdx.x * 4 + wid) * 4 + grp;   // 0..65535
    int mat  = row >> 15;                  // 0 -> t, 1 -> s
    int r    = row & 32767;

    const f32x4* src = reinterpret_cast<const f32x4*>(
        (mat == 0 ? ft : fs) + (size_t)r * L_);
    unsigned short* dst = (mat == 0 ? outT : outS) + (size_t)r * LP;

    float ss = 0.0f;
#pragma unroll
    for (int it = 0; it < 12; ++it) {      // chunks 0..191, all lanes active
        int c = it * 16 + sub;
        f32x4 v = src[c];
        ss += v.x * v.x + v.y * v.y + v.z * v.z + v.w * v.w;
        ushort4 o;
        o.x = f2bf(v.x); o.y = f2bf(v.y); o.z = f2bf(v.z); o.w = f2bf(v.w);
        *reinterpret_cast<ushort4*>(dst + (size_t)c * 4) = o;
    }
    // tail line [1536,1664): chunks 192..195 data (sub<4), 196..207 zeros —
    // 16 lanes cover the full 128B line
    {
        ushort4 o = make_ushort4(0, 0, 0, 0);
        if (sub < 4) {
            f32x4 v = src[192 + sub];
            ss += v.x * v.x + v.y * v.y + v.z * v.z + v.w * v.w;
            o.x = f2bf(v.x); o.y = f2bf(v.y); o.z = f2bf(v.z); o.w = f2bf(v.w);
        }
        *reinterpret_cast<ushort4*>(dst + (size_t)(192 + sub) * 4) = o;
    }
    // 16-lane group reduction
#pragma unroll
    for (int m = 8; m >= 1; m >>= 1) ss += __shfl_xor(ss, m, 64);
    if (sub == 0)
        (mat == 0 ? rnT : rnS)[r] = 1.0f / fmaxf(sqrtf(ss), 1e-12f);
}

// ---------------------------------------------------------------------------
// Pass 2 (fused, 4-phase schedule, R8/R11 verified structure). One block per
// (batch, pair{i<=j}), full K (25 steps, k<800). Panels RAW bf16;
// normalization applied in the epilogue: sum (G*rn_i*rn_j)^2;
// C/D layout col=lane&15, row=4*(lane>>4)+q.
__global__ __launch_bounds__(512, 1) void gram_kernel(
    const unsigned short* __restrict__ Tn,
    const unsigned short* __restrict__ Sn,
    const float* __restrict__ rnT,
    const float* __restrict__ rnS,
    float* __restrict__ partials)
{
    // T1: bijective XCD chunk swizzle (640 = 8 XCDs x 80; 8 batches/XCD)
    int blk = (blockIdx.x % NXCD) * (B_ * NPAIR / NXCD) + blockIdx.x / NXCD;
    int b   = blk / NPAIR;
    int t   = blk % NPAIR;

    int i, j;
    if      (t < 4) { i = 0; j = t;     }
    else if (t < 7) { i = 1; j = t - 3; }
    else if (t < 9) { i = 2; j = t - 5; }
    else            { i = 3; j = 3;     }

    float wsym   = (i == j) ? 1.0f : 2.0f;
    float wcross = (i == j) ? 0.5f : 1.0f;

    const unsigned short* Ti = Tn + (size_t)b * C_ * LP + (size_t)i * TILE * LP;
    const unsigned short* Tj = Tn + (size_t)b * C_ * LP + (size_t)j * TILE * LP;
    const unsigned short* Si = Sn + (size_t)b * C_ * LP + (size_t)i * TILE * LP;
    const unsigned short* Sj = Sn + (size_t)b * C_ * LP + (size_t)j * TILE * LP;

    __shared__ unsigned short lds[3 * 16384];
    __shared__ float red[8];
    __shared__ float nTi[128], nTj[128], nSi[128], nSj[128];

    int tid  = threadIdx.x;
    int wid  = tid >> 6;
    int lane = tid & 63;

    // stage the 4 norm vectors (consumed only in the epilogue)
    {
        int q = tid & 127;
        const float* srcv;
        float* dstv;
        switch (tid >> 7) {
            case 0: srcv = rnT + b * C_ + i * TILE; dstv = nTi; break;
            case 1: srcv = rnT + b * C_ + j * TILE; dstv = nTj; break;
            case 2: srcv = rnS + b * C_ + i * TILE; dstv = nSi; break;
            default: srcv = rnS + b * C_ + j * TILE; dstv = nSj; break;
        }
        dstv[q] = srcv[q];
    }

    // staging addresses (T2 swizzle by pre-swizzled global source slot)
    int sr  = tid >> 2;                      // panel row 0..127
    int ssl = (tid & 3) ^ ((sr >> 1) & 3);   // swizzled 16B slot in row
    const size_t gOff = (size_t)sr * LP + ssl * 8;   // + k0 per step
    const int dOff = wid * 512;              // shorts; lane*16B implicit

    // fragment read addresses (swizzled read side, involution matches source)
    int rA = (wid >> 2) * 64 + (lane & 15);  // A-side panel row
    int rB = (wid & 3) * 32 + (lane & 15);   // B-side panel row
    int kb = (lane >> 4) * 16;               // 16B k-slot (bytes)
    int aByte = rA * 64 + (kb ^ (((rA >> 1) & 3) << 4));
    int bByte = rB * 64 + (kb ^ (((rB >> 1) & 3) << 4));

    f32x4 att[4][2] = {}, ast[4][2] = {}, ats[4][2] = {}, ass[4][2] = {};

    unsigned short* c0 = lds;
    unsigned short* c1 = lds + 16384;
    unsigned short* c2 = lds + 32768;

    // prologue: stage tiles 0,1 (8 GLD/thread outstanding)
    {
        GLD16(Ti + gOff, c0 + dOff);  GLD16(Tj + gOff, c0 + 4096 + dOff);
        GLD16(Si + gOff, c0 + 8192 + dOff);  GLD16(Sj + gOff, c0 + 12288 + dOff);
        GLD16(Ti + gOff + 32, c1 + dOff);  GLD16(Tj + gOff + 32, c1 + 4096 + dOff);
        GLD16(Si + gOff + 32, c1 + 8192 + dOff);  GLD16(Sj + gOff + 32, c1 + 12288 + dOff);
    }
    WAITV4;                 // tile 0 landed; tile 1's 4 loads in flight
    SBAR; SCHED0;

#define MFMA8(ACC, FA, FB)                                                             \
    _Pragma("unroll")                                                                  \
    for (int m = 0; m < 4; ++m)                                                        \
        _Pragma("unroll")                                                              \
        for (int n = 0; n < 2; ++n)                                                    \
            ACC[m][n] = __builtin_amdgcn_mfma_f32_16x16x32_bf16(FA[m], FB[n], ACC[m][n], 0, 0, 0);

#define KSTEP(BUF, NBUF, K2, DOSTAGE, ENDW)                                            \
    {                                                                                  \
        const char* bufc = (const char*)(BUF);                                         \
        bf16x8 fTi[4], fSi[4], fTj[2], fSj[2];                                         \
        /* ---- phase 0: read fTi,fTj | stage Ti(t+2) | mfma tt ---- */                \
        _Pragma("unroll")                                                              \
        for (int m = 0; m < 4; ++m)                                                    \
            fTi[m] = *reinterpret_cast<const bf16x8*>(bufc + aByte + m * 1024);        \
        _Pragma("unroll")                                                              \
        for (int n = 0; n < 2; ++n)                                                    \
            fTj[n] = *reinterpret_cast<const bf16x8*>(bufc + 8192 + bByte + n * 1024); \
        if (DOSTAGE) GLD16(Ti + gOff + (K2), (NBUF) + dOff);                           \
        SBAR; LGKM0; SCHED0;                                                           \
        __builtin_amdgcn_s_setprio(1);                                                 \
        MFMA8(att, fTi, fTj);                                                          \
        __builtin_amdgcn_s_setprio(0);                                                 \
        SBAR;                                                                          \
        /* ---- phase 1: read fSj | stage Tj(t+2) | mfma st ---- */                    \
        _Pragma("unroll")                                                              \
        for (int n = 0; n < 2; ++n)                                                    \
            fSj[n] = *reinterpret_cast<const bf16x8*>(bufc + 24576 + bByte + n * 1024);\
        if (DOSTAGE) GLD16(Tj + gOff + (K2), (NBUF) + 4096 + dOff);                    \
        SBAR; LGKM0; SCHED0;                                                           \
        __builtin_amdgcn_s_setprio(1);                                                 \
        MFMA8(ast, fTi, fSj);                                                          \
        __builtin_amdgcn_s_setprio(0);                                                 \
        SBAR;                                                                          \
        /* ---- phase 2: read fSi | stage Si(t+2) | mfma ts ---- */                    \
        _Pragma("unroll")                                                              \
        for (int m = 0; m < 4; ++m)                                                    \
            fSi[m] = *reinterpret_cast<const bf16x8*>(bufc + 16384 + aByte + m * 1024);\
        if (DOSTAGE) GLD16(Si + gOff + (K2), (NBUF) + 8192 + dOff);                    \
        SBAR; LGKM0; SCHED0;                                                           \
        __builtin_amdgcn_s_setprio(1);                                                 \
        MFMA8(ats, fSi, fTj);                                                          \
        __builtin_amdgcn_s_setprio(0);                                                 \
        SBAR;                                                                          \
        /* ---- phase 3: stage Sj(t+2) | mfma ss | end-of-step wait ---- */            \
        if (DOSTAGE) GLD16(Sj + gOff + (K2), (NBUF) + 12288 + dOff);                   \
        __builtin_amdgcn_s_setprio(1);                                                 \
        MFMA8(ass, fSi, fSj);                                                          \
        __builtin_amdgcn_s_setprio(0);                                                 \
        ENDW;                                                                          \
        SBAR; SCHED0;                                                                  \
    }

    for (int s = 0; s < KSTEPS - 2; ++s) {
        KSTEP(c0, c2, (s + 2) * 32, 1, WAITV4);
        unsigned short* tmp = c0; c0 = c1; c1 = c2; c2 = tmp;
    }
    KSTEP(c0, c2, 0, 0, WAITV0);
    { unsigned short* tmp = c0; c0 = c1; c1 = tmp; }
    KSTEP(c0, c2, 0, 0, (void)0);

    // ---- epilogue: normalize-and-square with per-element rn scaling ----
    int wrow0 = (wid >> 2) * 64 + 4 * (lane >> 4);
    int wcol0 = (wid & 3) * 32 + (lane & 15);
    float v = 0.0f;
#pragma unroll
    for (int m = 0; m < 4; ++m)
#pragma unroll
        for (int q = 0; q < 4; ++q) {
            int rr = wrow0 + m * 16 + q;
            float rTi = nTi[rr], rSi = nSi[rr];
#pragma unroll
            for (int n = 0; n < 2; ++n) {
                int cc = wcol0 + n * 16;
                float rTj = nTj[cc], rSj = nSj[cc];
                float x0 = att[m][n][q] * rTi * rTj;
                float x1 = ass[m][n][q] * rSi * rSj;
                float x2 = ast[m][n][q] * rTi * rSj;
                float x3 = ats[m][n][q] * rSi * rTj;
                v += wsym * (x0 * x0 + x1 * x1)
                   - 2.0f * wcross * (x2 * x2 + x3 * x3);
            }
        }
#pragma unroll
    for (int m = 32; m >= 1; m >>= 1) v += __shfl_xor(v, m, 64);
    if (lane == 0) red[wid] = v;
    __syncthreads();
    if (tid == 0) {
        float tot = 0.0f;
#pragma unroll
        for (int q = 0; q < 8; ++q) tot += red[q];
        atomicAdd(&partials[0], tot);
    }
}

// ---------------------------------------------------------------------------
__global__ void finalize_kernel(const float* __restrict__ partials, float* __restrict__ out) {
    // mean over B*C*C = 64*512*512 = 16777216
    out[0] = partials[0] * (1.0f / 16777216.0f);
}

// ---------------------------------------------------------------------------
extern "C" void kernel_launch(void* const* d_in, const int* in_sizes, int n_in,
                              void* d_out, int out_size, void* d_ws, size_t ws_size,
                              hipStream_t stream) {
    const float* fs = (const float*)d_in[0];   // fm_s
    const float* ft = (const float*)d_in[1];   // fm_t
    float* out = (float*)d_out;

    char* ws = (char*)d_ws;
    const size_t SZ = (size_t)B_ * C_ * LP * 2;                    // 54525952 B
    float* partials = (float*)ws;                                  // 64 B
    unsigned short* Tn = (unsigned short*)(ws + 256);
    unsigned short* Sn = (unsigned short*)(ws + 256 + SZ);
    float* rnT = (float*)(ws + 256 + 2 * SZ);                      // 128 KB
    float* rnS = (float*)(ws + 256 + 2 * SZ + 131072);             // 128 KB
    // total ws use: ~109.3 MB

    hipLaunchKernelGGL(normalize_kernel, dim3(NROWS / 16), dim3(256), 0, stream,
                       fs, ft, Tn, Sn, rnT, rnS, partials);
    hipLaunchKernelGGL(gram_kernel, dim3(B_ * NPAIR), dim3(512), 0, stream,
                       Tn, Sn, rnT, rnS, partials);
    hipLaunchKernelGGL(finalize_kernel, dim3(1), dim3(1), 0, stream, partials, out);
}